// Round 2
// baseline (894.069 us; speedup 1.0000x reference)
//
#include <hip/hip_runtime.h>
#include <hip/hip_bf16.h>

#define NB 2
#define SEQ 2048
#define DM 384
#define NH 8
#define HD 48
#define QKVN 1152
#define QKVE (NB*NH*SEQ*HD)   // 1572864 elements per q/k/v buffer

typedef __hip_bfloat16 bf16;
static __device__ __forceinline__ float bf2f(bf16 v){ return __bfloat162float(v); }

// dtype-agnostic input load: isf=1 -> fp32, isf=0 -> bf16
static __device__ __forceinline__ float ldin(const void* p, size_t i, int isf){
    return isf ? ((const float*)p)[i] : bf2f(((const bf16*)p)[i]);
}

// ---------------- K0: detect input dtype. Even bf16-indexed elements of fp32 data
// are low-mantissa garbage (log-uniform magnitude); of bf16 data they are ~N(0,1).
__global__ void k_detect(const void* __restrict__ x, int* __restrict__ flag)
{
    int t = threadIdx.x;  // 64 threads = 1 wave
    const bf16* xb = (const bf16*)x;
    float v = bf2f(xb[2*t]);
    float a = fabsf(v);
    int good = (v == 0.0f) || (a > 9.765625e-4f && a < 1024.0f);  // 2^-10 .. 2^10
    unsigned long long m = __ballot(good);
    if (t == 0) *flag = (__popcll(m) >= 32) ? 0 : 1;   // 0 = bf16, 1 = fp32
}

// ---------------- K1: qkv = x @ W_qkv + b_qkv, scattered to q/k/v [b*h][n][48] fp32
__global__ __launch_bounds__(256) void k_qkv(const void* __restrict__ x,
    const void* __restrict__ W, const void* __restrict__ bias,
    float* __restrict__ q, float* __restrict__ k, float* __restrict__ v,
    const int* __restrict__ flag)
{
    __shared__ float xs[32][33];
    __shared__ float wt[32][129];
    const int isf = *flag;
    const int t = threadIdx.x;
    const int mt = blockIdx.x / 9, nt = blockIdx.x % 9;
    const int row0 = mt*32, col0 = nt*128;
    const int rg = t >> 5, cg = t & 31;
    float acc[4][4] = {};
    for (int k0 = 0; k0 < DM; k0 += 32) {
        __syncthreads();
        for (int idx = t; idx < 32*32; idx += 256) {
            int r = idx >> 5, kk = idx & 31;
            xs[r][kk] = ldin(x, (size_t)(row0+r)*DM + k0 + kk, isf);
        }
        for (int idx = t; idx < 32*128; idx += 256) {
            int kk = idx >> 7, cc = idx & 127;
            wt[kk][cc] = ldin(W, (size_t)(k0+kk)*QKVN + col0 + cc, isf);
        }
        __syncthreads();
        #pragma unroll
        for (int kk = 0; kk < 32; ++kk) {
            float a0=xs[rg][kk], a1=xs[rg+8][kk], a2=xs[rg+16][kk], a3=xs[rg+24][kk];
            float b0=wt[kk][cg], b1=wt[kk][cg+32], b2=wt[kk][cg+64], b3=wt[kk][cg+96];
            acc[0][0]+=a0*b0; acc[0][1]+=a0*b1; acc[0][2]+=a0*b2; acc[0][3]+=a0*b3;
            acc[1][0]+=a1*b0; acc[1][1]+=a1*b1; acc[1][2]+=a1*b2; acc[1][3]+=a1*b3;
            acc[2][0]+=a2*b0; acc[2][1]+=a2*b1; acc[2][2]+=a2*b2; acc[2][3]+=a2*b3;
            acc[3][0]+=a3*b0; acc[3][1]+=a3*b1; acc[3][2]+=a3*b2; acc[3][3]+=a3*b3;
        }
    }
    #pragma unroll
    for (int ii = 0; ii < 4; ++ii) {
        int row = row0 + rg + 8*ii;
        int bi = row >> 11, nn = row & (SEQ-1);
        #pragma unroll
        for (int jj = 0; jj < 4; ++jj) {
            int col = col0 + cg + 32*jj;
            int which = col / DM, c2 = col % DM;
            int hh = c2 / HD, dd = c2 % HD;
            float val = acc[ii][jj] + ldin(bias, col, isf);
            float* dst = (which == 0) ? q : ((which == 1) ? k : v);
            dst[(size_t)((bi*NH + hh)*SEQ + nn)*HD + dd] = val;
        }
    }
}

// ---------------- K2: flash attention with distance bias. 32 i-rows/block, 64-j tiles.
__global__ __launch_bounds__(256) void k_attn(const float* __restrict__ qg,
    const float* __restrict__ kg, const float* __restrict__ vg,
    const void* __restrict__ coords, const void* __restrict__ Wdist,
    const void* __restrict__ bdist, float* __restrict__ ao,
    const int* __restrict__ flag)
{
    __shared__ __align__(16) float qs[32][52];
    __shared__ __align__(16) float ks[64][52];
    __shared__ __align__(16) float vsT[48][68];
    __shared__ __align__(16) float ps[32][68];
    __shared__ float cix[32], ciy[32], ciz[32];
    __shared__ float cjx[64], cjy[64], cjz[64];
    __shared__ float pmax[32][16], psum[32][16];
    __shared__ float mrow[32], lrow[32], mnewS[32], arow[32];

    const int isf = *flag;
    const int t = threadIdx.x;
    const int bh = blockIdx.x >> 6;      // 0..15
    const int it = blockIdx.x & 63;
    const int bi = bh >> 3, hh = bh & 7;
    const int i0 = it * 32;
    const int i2 = t & 15;               // rows {i2, i2+16}
    const int jg = t >> 4;               // 0..15 -> js {jg, jg+16, jg+32, jg+48}
    const int pc = (t >> 4) * 3;         // PV cols pc..pc+2
    const float scale = 0.14433756729740643f; // 1/sqrt(48)
    const float wd = ldin(Wdist, hh, isf), bd = ldin(bdist, hh, isf);

    for (int idx = t; idx < 32*48; idx += 256) {
        int r = idx / 48, d = idx - r*48;
        qs[r][d] = qg[((size_t)bh*SEQ + i0 + r)*HD + d];
    }
    if (t < 32) {
        int gi = (bi*SEQ + i0 + t)*3;
        cix[t] = ldin(coords, gi, isf);
        ciy[t] = ldin(coords, gi+1, isf);
        ciz[t] = ldin(coords, gi+2, isf);
        mrow[t] = -1e30f; lrow[t] = 0.f;
    }
    float o0[3] = {0,0,0}, o1[3] = {0,0,0};

    const float4* qs4 = reinterpret_cast<const float4*>(&qs[0][0]);
    const float4* ks4 = reinterpret_cast<const float4*>(&ks[0][0]);
    const float4* ps4 = reinterpret_cast<const float4*>(&ps[0][0]);
    const float4* vT4 = reinterpret_cast<const float4*>(&vsT[0][0]);

    for (int jt = 0; jt < SEQ/64; ++jt) {
        const int j0 = jt*64;
        __syncthreads();  // (A) prior PV done before overwriting ks/vsT/cj
        for (int idx = t; idx < 64*48; idx += 256) {
            int r = idx / 48, d = idx - r*48;
            size_t g = ((size_t)bh*SEQ + j0 + r)*HD + d;
            ks[r][d] = kg[g];
            vsT[d][r] = vg[g];
        }
        if (t < 64) {
            int gj = (bi*SEQ + j0 + t)*3;
            cjx[t] = ldin(coords, gj, isf);
            cjy[t] = ldin(coords, gj+1, isf);
            cjz[t] = ldin(coords, gj+2, isf);
        }
        __syncthreads();  // (B)
        float s0[4] = {0,0,0,0}, s1[4] = {0,0,0,0};
        #pragma unroll
        for (int d4 = 0; d4 < 12; ++d4) {
            float4 qa = qs4[i2*13 + d4];
            float4 qb = qs4[(i2+16)*13 + d4];
            #pragma unroll
            for (int m = 0; m < 4; ++m) {
                float4 kv = ks4[(jg + 16*m)*13 + d4];
                s0[m] += qa.x*kv.x + qa.y*kv.y + qa.z*kv.z + qa.w*kv.w;
                s1[m] += qb.x*kv.x + qb.y*kv.y + qb.z*kv.z + qb.w*kv.w;
            }
        }
        float lg0[4], lg1[4];
        float tm0 = -1e30f, tm1 = -1e30f;
        float axx = cix[i2], ayy = ciy[i2], azz = ciz[i2];
        float bxx = cix[i2+16], byy = ciy[i2+16], bzz = ciz[i2+16];
        #pragma unroll
        for (int m = 0; m < 4; ++m) {
            int j = jg + 16*m;
            float dx = axx - cjx[j], dy = ayy - cjy[j], dz = azz - cjz[j];
            float dist0 = sqrtf(dx*dx + dy*dy + dz*dz);
            dx = bxx - cjx[j]; dy = byy - cjy[j]; dz = bzz - cjz[j];
            float dist1 = sqrtf(dx*dx + dy*dy + dz*dz);
            lg0[m] = s0[m]*scale + dist0*wd + bd;
            lg1[m] = s1[m]*scale + dist1*wd + bd;
            tm0 = fmaxf(tm0, lg0[m]);
            tm1 = fmaxf(tm1, lg1[m]);
        }
        pmax[i2][jg] = tm0; pmax[i2+16][jg] = tm1;
        __syncthreads();  // (C)
        if (t < 32) {
            float mx = mrow[t];
            #pragma unroll
            for (int g2 = 0; g2 < 16; ++g2) mx = fmaxf(mx, pmax[t][g2]);
            mnewS[t] = mx;
            arow[t] = __expf(mrow[t] - mx);
            mrow[t] = mx;
        }
        __syncthreads();  // (D)
        {
            float m0 = mnewS[i2], m1 = mnewS[i2+16];
            float su0 = 0.f, su1 = 0.f;
            #pragma unroll
            for (int m = 0; m < 4; ++m) {
                float e0 = __expf(lg0[m] - m0);
                float e1 = __expf(lg1[m] - m1);
                ps[i2][jg + 16*m] = e0;
                ps[i2+16][jg + 16*m] = e1;
                su0 += e0; su1 += e1;
            }
            psum[i2][jg] = su0; psum[i2+16][jg] = su1;
        }
        __syncthreads();  // (E)
        if (t < 32) {
            float s = 0.f;
            #pragma unroll
            for (int g2 = 0; g2 < 16; ++g2) s += psum[t][g2];
            lrow[t] = lrow[t]*arow[t] + s;
        }
        float a0 = arow[i2], a1 = arow[i2+16];
        #pragma unroll
        for (int c = 0; c < 3; ++c) { o0[c] *= a0; o1[c] *= a1; }
        #pragma unroll
        for (int j4 = 0; j4 < 16; ++j4) {
            float4 p0 = ps4[i2*17 + j4];
            float4 p1 = ps4[(i2+16)*17 + j4];
            float4 va = vT4[(pc+0)*17 + j4];
            float4 vb = vT4[(pc+1)*17 + j4];
            float4 vc = vT4[(pc+2)*17 + j4];
            o0[0] += p0.x*va.x + p0.y*va.y + p0.z*va.z + p0.w*va.w;
            o0[1] += p0.x*vb.x + p0.y*vb.y + p0.z*vb.z + p0.w*vb.w;
            o0[2] += p0.x*vc.x + p0.y*vc.y + p0.z*vc.z + p0.w*vc.w;
            o1[0] += p1.x*va.x + p1.y*va.y + p1.z*va.z + p1.w*va.w;
            o1[1] += p1.x*vb.x + p1.y*vb.y + p1.z*vb.z + p1.w*vb.w;
            o1[2] += p1.x*vc.x + p1.y*vc.y + p1.z*vc.z + p1.w*vc.w;
        }
    }
    __syncthreads();
    float il0 = 1.0f / lrow[i2], il1 = 1.0f / lrow[i2+16];
    size_t base0 = ((size_t)(bi*SEQ + i0 + i2))*DM + hh*HD + pc;
    size_t base1 = ((size_t)(bi*SEQ + i0 + i2 + 16))*DM + hh*HD + pc;
    #pragma unroll
    for (int c = 0; c < 3; ++c) {
        ao[base0 + c] = o0[c]*il0;
        ao[base1 + c] = o1[c]*il1;
    }
}

// ---------------- K3: out = ao @ W_out + b_out (fp32 A; W/bias/out dtype per flag)
__global__ __launch_bounds__(256) void k_out(const float* __restrict__ ao,
    const void* __restrict__ W, const void* __restrict__ bias, void* __restrict__ out,
    const int* __restrict__ flag)
{
    __shared__ float as_[32][33];
    __shared__ float wt[32][129];
    const int isf = *flag;
    const int t = threadIdx.x;
    const int mt = blockIdx.x / 3, nt = blockIdx.x % 3;
    const int row0 = mt*32, col0 = nt*128;
    const int rg = t >> 5, cg = t & 31;
    float acc[4][4] = {};
    for (int k0 = 0; k0 < DM; k0 += 32) {
        __syncthreads();
        for (int idx = t; idx < 32*32; idx += 256) {
            int r = idx >> 5, kk = idx & 31;
            as_[r][kk] = ao[(size_t)(row0+r)*DM + k0 + kk];
        }
        for (int idx = t; idx < 32*128; idx += 256) {
            int kk = idx >> 7, cc = idx & 127;
            wt[kk][cc] = ldin(W, (size_t)(k0+kk)*DM + col0 + cc, isf);
        }
        __syncthreads();
        #pragma unroll
        for (int kk = 0; kk < 32; ++kk) {
            float a0=as_[rg][kk], a1=as_[rg+8][kk], a2=as_[rg+16][kk], a3=as_[rg+24][kk];
            float b0=wt[kk][cg], b1=wt[kk][cg+32], b2=wt[kk][cg+64], b3=wt[kk][cg+96];
            acc[0][0]+=a0*b0; acc[0][1]+=a0*b1; acc[0][2]+=a0*b2; acc[0][3]+=a0*b3;
            acc[1][0]+=a1*b0; acc[1][1]+=a1*b1; acc[1][2]+=a1*b2; acc[1][3]+=a1*b3;
            acc[2][0]+=a2*b0; acc[2][1]+=a2*b1; acc[2][2]+=a2*b2; acc[2][3]+=a2*b3;
            acc[3][0]+=a3*b0; acc[3][1]+=a3*b1; acc[3][2]+=a3*b2; acc[3][3]+=a3*b3;
        }
    }
    #pragma unroll
    for (int ii = 0; ii < 4; ++ii) {
        int row = row0 + rg + 8*ii;
        #pragma unroll
        for (int jj = 0; jj < 4; ++jj) {
            int col = col0 + cg + 32*jj;
            float val = acc[ii][jj] + ldin(bias, col, isf);
            size_t oi = (size_t)row*DM + col;
            if (isf) ((float*)out)[oi] = val;
            else     ((bf16*)out)[oi]  = __float2bfloat16(val);
        }
    }
}

extern "C" void kernel_launch(void* const* d_in, const int* in_sizes, int n_in,
                              void* d_out, int out_size, void* d_ws, size_t ws_size,
                              hipStream_t stream) {
    const void* x      = d_in[0];
    const void* coords = d_in[1];
    const void* Wqkv   = d_in[2];
    const void* bqkv   = d_in[3];
    const void* Wdist  = d_in[4];
    const void* bdist  = d_in[5];
    const void* Wout   = d_in[6];
    const void* bout   = d_in[7];

    float* wsf = (float*)d_ws;
    float* q  = wsf;
    float* k  = wsf + (size_t)QKVE;
    float* v  = wsf + (size_t)2*QKVE;
    float* ao = wsf + (size_t)3*QKVE;
    int* flag = (int*)(wsf + (size_t)4*QKVE);

    k_detect<<<dim3(1), dim3(64), 0, stream>>>(x, flag);
    k_qkv<<<dim3(128*9), dim3(256), 0, stream>>>(x, Wqkv, bqkv, q, k, v, flag);
    k_attn<<<dim3(16*64), dim3(256), 0, stream>>>(q, k, v, coords, Wdist, bdist, ao, flag);
    k_out<<<dim3(128*3), dim3(256), 0, stream>>>(ao, Wout, bout, d_out, flag);
}

// Round 3
// 468.316 us; speedup vs baseline: 1.9091x; 1.9091x over previous
//
#include <hip/hip_runtime.h>
#include <hip/hip_bf16.h>
#include <string.h>

#define NB 2
#define SEQ 2048
#define DM 384
#define NH 8
#define HD 48
#define HDP 64                      // padded head dim for MFMA (d 48..63 = 0)
#define QKVN 1152
#define BH (NB*NH)                  // 16
#define QKVE_P ((size_t)BH*SEQ*HDP) // 2,097,152 bf16 elements per q/k/v buffer

typedef __hip_bfloat16 bf16;
typedef __attribute__((ext_vector_type(8))) short short8;
typedef __attribute__((ext_vector_type(4))) float float4v;

static __device__ __forceinline__ float bf2f(bf16 v){ return __bfloat162float(v); }

// dtype-agnostic input load: isf=1 -> fp32, isf=0 -> bf16
static __device__ __forceinline__ float ldin(const void* p, size_t i, int isf){
    return isf ? ((const float*)p)[i] : bf2f(((const bf16*)p)[i]);
}

// fp32 -> bf16 bits, round-to-nearest-even
static __device__ __forceinline__ short f2b(float f){
    union { float f; unsigned u; } a; a.f = f;
    unsigned r = a.u + 0x7FFFu + ((a.u >> 16) & 1u);
    return (short)(r >> 16);
}

// ---------------- K0: detect input dtype (0 = bf16, 1 = fp32)
__global__ void k_detect(const void* __restrict__ x, int* __restrict__ flag)
{
    int t = threadIdx.x;  // 64 threads = 1 wave
    const bf16* xb = (const bf16*)x;
    float v = bf2f(xb[2*t]);
    float a = fabsf(v);
    int good = (v == 0.0f) || (a > 9.765625e-4f && a < 1024.0f);
    unsigned long long m = __ballot(good);
    if (t == 0) *flag = (__popcll(m) >= 32) ? 0 : 1;
}

// ---------------- K1: qkv = x @ W_qkv + b_qkv, scattered to q/k/v bf16 [b*h][n][64]
__global__ __launch_bounds__(256) void k_qkv(const void* __restrict__ x,
    const void* __restrict__ W, const void* __restrict__ bias,
    short* __restrict__ q, short* __restrict__ k, short* __restrict__ v,
    const int* __restrict__ flag)
{
    __shared__ float xs[32][33];
    __shared__ float wt[32][129];
    const int isf = *flag;
    const int t = threadIdx.x;
    const int mt = blockIdx.x / 9, nt = blockIdx.x % 9;
    const int row0 = mt*32, col0 = nt*128;
    const int rg = t >> 5, cg = t & 31;
    float acc[4][4] = {};
    for (int k0 = 0; k0 < DM; k0 += 32) {
        __syncthreads();
        for (int idx = t; idx < 32*32; idx += 256) {
            int r = idx >> 5, kk = idx & 31;
            xs[r][kk] = ldin(x, (size_t)(row0+r)*DM + k0 + kk, isf);
        }
        for (int idx = t; idx < 32*128; idx += 256) {
            int kk = idx >> 7, cc = idx & 127;
            wt[kk][cc] = ldin(W, (size_t)(k0+kk)*QKVN + col0 + cc, isf);
        }
        __syncthreads();
        #pragma unroll
        for (int kk = 0; kk < 32; ++kk) {
            float a0=xs[rg][kk], a1=xs[rg+8][kk], a2=xs[rg+16][kk], a3=xs[rg+24][kk];
            float b0=wt[kk][cg], b1=wt[kk][cg+32], b2=wt[kk][cg+64], b3=wt[kk][cg+96];
            acc[0][0]+=a0*b0; acc[0][1]+=a0*b1; acc[0][2]+=a0*b2; acc[0][3]+=a0*b3;
            acc[1][0]+=a1*b0; acc[1][1]+=a1*b1; acc[1][2]+=a1*b2; acc[1][3]+=a1*b3;
            acc[2][0]+=a2*b0; acc[2][1]+=a2*b1; acc[2][2]+=a2*b2; acc[2][3]+=a2*b3;
            acc[3][0]+=a3*b0; acc[3][1]+=a3*b1; acc[3][2]+=a3*b2; acc[3][3]+=a3*b3;
        }
    }
    #pragma unroll
    for (int ii = 0; ii < 4; ++ii) {
        int row = row0 + rg + 8*ii;
        int bi = row >> 11, nn = row & (SEQ-1);
        #pragma unroll
        for (int jj = 0; jj < 4; ++jj) {
            int col = col0 + cg + 32*jj;
            int which = col / DM, c2 = col % DM;
            int hh = c2 / HD, dd = c2 % HD;
            float val = acc[ii][jj] + ldin(bias, col, isf);
            short* dst = (which == 0) ? q : ((which == 1) ? k : v);
            dst[(size_t)((bi*NH + hh)*SEQ + nn)*HDP + dd] = f2b(val);
        }
    }
}

// ---------------- K2: MFMA flash attention with distance bias.
// Block: one (b,h), 64 i-rows; 4 waves x 16 rows. j-tiles of 64.
__global__ __launch_bounds__(256) void k_attn(
    const short* __restrict__ qg, const short* __restrict__ kg, const short* __restrict__ vg,
    const void* __restrict__ coords, const void* __restrict__ Wdist,
    const void* __restrict__ bdist, float* __restrict__ ao, const int* __restrict__ flag)
{
    __shared__ __align__(16) short Qs[64*72];
    __shared__ __align__(16) short Ks[64*72];
    __shared__ __align__(16) short Vt[48*72];   // V^T [d][j], j-blocks-of-8 XOR-swizzled
    __shared__ __align__(16) short Ps[4][16*72];
    __shared__ float cix[64], ciy[64], ciz[64];
    __shared__ float cjx[64], cjy[64], cjz[64];

    const int isf = *flag;
    const int t = threadIdx.x;
    const int w = t >> 6;           // wave 0..3
    const int lane = t & 63;
    const int L = lane & 15;
    const int quad = lane >> 4;
    const int bh = blockIdx.x >> 5; // 16 bh x 32 i-tiles
    const int it = blockIdx.x & 31;
    const int bi = bh >> 3, hh = bh & 7;
    const int i0 = it * 64;
    const float scale = 0.14433756729740643f; // 1/sqrt(48)
    const float wd = ldin(Wdist, hh, isf), bd = ldin(bdist, hh, isf);

    // stage Q tile (64 x 64 bf16) -> Qs[64][72]
    #pragma unroll
    for (int p = 0; p < 2; ++p) {
        int c = t + p*256;               // 512 chunks of 8 shorts
        int row = c >> 3, col8 = c & 7;
        *(int4*)(&Qs[row*72 + col8*8]) =
            *(const int4*)(qg + ((size_t)(bh*SEQ) + i0 + row)*HDP + col8*8);
    }
    if (t < 64) {
        int gi = (bi*SEQ + i0 + t)*3;
        cix[t] = ldin(coords, gi, isf);
        ciy[t] = ldin(coords, gi+1, isf);
        ciz[t] = ldin(coords, gi+2, isf);
    }
    __syncthreads();

    // Q A-frags for this wave: rows 16w+L, k-chunks {0,32}
    const short8 qa0 = *(const short8*)(&Qs[(16*w + L)*72 + quad*8]);
    const short8 qa1 = *(const short8*)(&Qs[(16*w + L)*72 + 32 + quad*8]);
    // ci for this lane's C-rows: i_loc = 16w + quad*4 + r
    float cxr[4], cyr[4], czr[4];
    #pragma unroll
    for (int r = 0; r < 4; ++r) {
        int ir = 16*w + quad*4 + r;
        cxr[r] = cix[ir]; cyr[r] = ciy[ir]; czr[r] = ciz[ir];
    }

    float mrow[4], lrow[4];
    #pragma unroll
    for (int r = 0; r < 4; ++r) { mrow[r] = -1e30f; lrow[r] = 0.f; }
    float4v accO[3] = {};

    for (int j0 = 0; j0 < SEQ; j0 += 64) {
        __syncthreads();  // previous iteration's readers done before restaging
        // stage K -> Ks[64][72]; V -> Vt[d][j] transposed + swizzled; cj
        #pragma unroll
        for (int p = 0; p < 2; ++p) {
            int c = t + p*256;
            int row = c >> 3, col8 = c & 7;
            size_t gbase = ((size_t)(bh*SEQ) + j0 + row)*HDP + col8*8;
            *(int4*)(&Ks[row*72 + col8*8]) = *(const int4*)(kg + gbase);
            if (col8 < 6) {   // d = col8*8+e < 48 only
                union { int4 v; short s[8]; } uv;
                uv.v = *(const int4*)(vg + gbase);
                int jb2 = (row >> 3) ^ col8;   // swizzle key = (d>>3)&7 = col8
                #pragma unroll
                for (int e = 0; e < 8; ++e) {
                    int d = col8*8 + e;
                    Vt[d*72 + jb2*8 + (row & 7)] = uv.s[e];
                }
            }
        }
        if (t < 64) {
            int gj = (bi*SEQ + j0 + t)*3;
            cjx[t] = ldin(coords, gj, isf);
            cjy[t] = ldin(coords, gj+1, isf);
            cjz[t] = ldin(coords, gj+2, isf);
        }
        __syncthreads();

        // ---- S = Q K^T : 4 j-subtiles x 2 k-chunks
        float4v sacc[4] = {};
        #pragma unroll
        for (int nt = 0; nt < 4; ++nt) {
            short8 b0 = *(const short8*)(&Ks[(16*nt + L)*72 + quad*8]);
            sacc[nt] = __builtin_amdgcn_mfma_f32_16x16x32_bf16(qa0, b0, sacc[nt], 0, 0, 0);
            short8 b1 = *(const short8*)(&Ks[(16*nt + L)*72 + 32 + quad*8]);
            sacc[nt] = __builtin_amdgcn_mfma_f32_16x16x32_bf16(qa1, b1, sacc[nt], 0, 0, 0);
        }

        // ---- logits = S*scale + dist*wd + bd ; row-max
        float lg[4][4];
        float tmax[4] = {-1e30f, -1e30f, -1e30f, -1e30f};
        #pragma unroll
        for (int nt = 0; nt < 4; ++nt) {
            float jx = cjx[16*nt + L], jy = cjy[16*nt + L], jz = cjz[16*nt + L];
            #pragma unroll
            for (int r = 0; r < 4; ++r) {
                float dx = cxr[r] - jx, dy = cyr[r] - jy, dz = czr[r] - jz;
                float dist = sqrtf(dx*dx + dy*dy + dz*dz);
                float v = sacc[nt][r]*scale + dist*wd + bd;
                lg[nt][r] = v;
                tmax[r] = fmaxf(tmax[r], v);
            }
        }
        #pragma unroll
        for (int r = 0; r < 4; ++r) {
            #pragma unroll
            for (int m = 1; m < 16; m <<= 1)
                tmax[r] = fmaxf(tmax[r], __shfl_xor(tmax[r], m, 16));
        }

        // ---- online softmax update (quad-local rows)
        float alpha[4], rsum[4];
        #pragma unroll
        for (int r = 0; r < 4; ++r) {
            float mn = fmaxf(mrow[r], tmax[r]);
            alpha[r] = __expf(mrow[r] - mn);
            mrow[r] = mn;
            rsum[r] = 0.f;
        }
        #pragma unroll
        for (int nt = 0; nt < 4; ++nt) {
            #pragma unroll
            for (int r = 0; r < 4; ++r) {
                float p = __expf(lg[nt][r] - mrow[r]);
                rsum[r] += p;
                Ps[w][(quad*4 + r)*72 + nt*16 + L] = f2b(p);
            }
        }
        #pragma unroll
        for (int r = 0; r < 4; ++r) {
            #pragma unroll
            for (int m = 1; m < 16; m <<= 1)
                rsum[r] += __shfl_xor(rsum[r], m, 16);
            lrow[r] = lrow[r]*alpha[r] + rsum[r];
        }
        #pragma unroll
        for (int dt = 0; dt < 3; ++dt)
            #pragma unroll
            for (int r = 0; r < 4; ++r)
                accO[dt][r] *= alpha[r];

        // ---- O += P V  (A = P from per-wave LDS; B = V^T swizzled)
        short8 pa0 = *(const short8*)(&Ps[w][L*72 + quad*8]);
        short8 pa1 = *(const short8*)(&Ps[w][L*72 + 32 + quad*8]);
        #pragma unroll
        for (int dt = 0; dt < 3; ++dt) {
            int d = 16*dt + L;
            int key = (d >> 3) & 7;
            short8 b0 = *(const short8*)(&Vt[d*72 + ((quad ^ key) << 3)]);
            accO[dt] = __builtin_amdgcn_mfma_f32_16x16x32_bf16(pa0, b0, accO[dt], 0, 0, 0);
            short8 b1 = *(const short8*)(&Vt[d*72 + (((4 + quad) ^ key) << 3)]);
            accO[dt] = __builtin_amdgcn_mfma_f32_16x16x32_bf16(pa1, b1, accO[dt], 0, 0, 0);
        }
    }

    // epilogue: O /= l, write ao fp32 [b*n][384]
    float inv[4];
    #pragma unroll
    for (int r = 0; r < 4; ++r) inv[r] = 1.0f / lrow[r];
    #pragma unroll
    for (int r = 0; r < 4; ++r) {
        size_t row = (size_t)(bi*SEQ) + i0 + 16*w + quad*4 + r;
        #pragma unroll
        for (int dt = 0; dt < 3; ++dt)
            ao[row*DM + hh*HD + 16*dt + L] = accO[dt][r]*inv[r];
    }
}

// ---------------- K3: out = ao @ W_out + b_out (fp32 A; W/bias/out dtype per flag)
__global__ __launch_bounds__(256) void k_out(const float* __restrict__ ao,
    const void* __restrict__ W, const void* __restrict__ bias, void* __restrict__ out,
    const int* __restrict__ flag)
{
    __shared__ float as_[32][33];
    __shared__ float wt[32][129];
    const int isf = *flag;
    const int t = threadIdx.x;
    const int mt = blockIdx.x / 3, nt = blockIdx.x % 3;
    const int row0 = mt*32, col0 = nt*128;
    const int rg = t >> 5, cg = t & 31;
    float acc[4][4] = {};
    for (int k0 = 0; k0 < DM; k0 += 32) {
        __syncthreads();
        for (int idx = t; idx < 32*32; idx += 256) {
            int r = idx >> 5, kk = idx & 31;
            as_[r][kk] = ao[(size_t)(row0+r)*DM + k0 + kk];
        }
        for (int idx = t; idx < 32*128; idx += 256) {
            int kk = idx >> 7, cc = idx & 127;
            wt[kk][cc] = ldin(W, (size_t)(k0+kk)*DM + col0 + cc, isf);
        }
        __syncthreads();
        #pragma unroll
        for (int kk = 0; kk < 32; ++kk) {
            float a0=as_[rg][kk], a1=as_[rg+8][kk], a2=as_[rg+16][kk], a3=as_[rg+24][kk];
            float b0=wt[kk][cg], b1=wt[kk][cg+32], b2=wt[kk][cg+64], b3=wt[kk][cg+96];
            acc[0][0]+=a0*b0; acc[0][1]+=a0*b1; acc[0][2]+=a0*b2; acc[0][3]+=a0*b3;
            acc[1][0]+=a1*b0; acc[1][1]+=a1*b1; acc[1][2]+=a1*b2; acc[1][3]+=a1*b3;
            acc[2][0]+=a2*b0; acc[2][1]+=a2*b1; acc[2][2]+=a2*b2; acc[2][3]+=a2*b3;
            acc[3][0]+=a3*b0; acc[3][1]+=a3*b1; acc[3][2]+=a3*b2; acc[3][3]+=a3*b3;
        }
    }
    #pragma unroll
    for (int ii = 0; ii < 4; ++ii) {
        int row = row0 + rg + 8*ii;
        #pragma unroll
        for (int jj = 0; jj < 4; ++jj) {
            int col = col0 + cg + 32*jj;
            float val = acc[ii][jj] + ldin(bias, col, isf);
            size_t oi = (size_t)row*DM + col;
            if (isf) ((float*)out)[oi] = val;
            else     ((bf16*)out)[oi]  = __float2bfloat16(val);
        }
    }
}

extern "C" void kernel_launch(void* const* d_in, const int* in_sizes, int n_in,
                              void* d_out, int out_size, void* d_ws, size_t ws_size,
                              hipStream_t stream) {
    const void* x      = d_in[0];
    const void* coords = d_in[1];
    const void* Wqkv   = d_in[2];
    const void* bqkv   = d_in[3];
    const void* Wdist  = d_in[4];
    const void* bdist  = d_in[5];
    const void* Wout   = d_in[6];
    const void* bout   = d_in[7];

    short* qb = (short*)d_ws;
    short* kb = qb + QKVE_P;
    short* vb = kb + QKVE_P;
    float* ao = (float*)(vb + QKVE_P);
    int* flag = (int*)(ao + (size_t)NB*SEQ*DM);

    // zero q/k/v (pads d=48..63 must be 0 for MFMA K-chunks)
    hipMemsetAsync(qb, 0, 3*QKVE_P*sizeof(short), stream);

    k_detect<<<dim3(1), dim3(64), 0, stream>>>(x, flag);
    k_qkv<<<dim3(128*9), dim3(256), 0, stream>>>(x, Wqkv, bqkv, qb, kb, vb, flag);
    k_attn<<<dim3(BH*32), dim3(256), 0, stream>>>(qb, kb, vb, coords, Wdist, bdist, ao, flag);
    k_out<<<dim3(128*3), dim3(256), 0, stream>>>(ao, Wout, bout, d_out, flag);
}

// Round 4
// 244.437 us; speedup vs baseline: 3.6577x; 1.9159x over previous
//
#include <hip/hip_runtime.h>
#include <hip/hip_bf16.h>

#define NB 2
#define SEQ 2048
#define DM 384
#define NH 8
#define HD 48
#define HDP 64
#define QKVN 1152
#define BH (NB*NH)

typedef __hip_bfloat16 bf16;
typedef __attribute__((ext_vector_type(8))) short short8;
typedef __attribute__((ext_vector_type(4))) float float4v;

static __device__ __forceinline__ float bf2f(bf16 v){ return __bfloat162float(v); }
static __device__ __forceinline__ float ldin(const void* p, size_t i, int isf){
    return isf ? ((const float*)p)[i] : bf2f(((const bf16*)p)[i]);
}
// fp32 -> bf16 bits, RNE
static __device__ __forceinline__ short f2b(float f){
    union { float f; unsigned u; } a; a.f = f;
    unsigned r = a.u + 0x7FFFu + ((a.u >> 16) & 1u);
    return (short)(r >> 16);
}

// ---------------- K0: detect input dtype (0 = bf16, 1 = fp32)
__global__ void k_detect(const void* __restrict__ x, int* __restrict__ flag)
{
    int t = threadIdx.x;
    const bf16* xb = (const bf16*)x;
    float v = bf2f(xb[2*t]);
    float a = fabsf(v);
    int good = (v == 0.0f) || (a > 9.765625e-4f && a < 1024.0f);
    unsigned long long m = __ballot(good);
    if (t == 0) *flag = (__popcll(m) >= 32) ? 0 : 1;
}

// ---------------- K_prep: xb = bf16(x); WqkvT/WoutT transposed bf16; biases fp32
// grid sections: [0,768) xb | [768,1200) Wqkv^T | [1200,1344) Wout^T | [1344,1350) biases
__global__ __launch_bounds__(256) void k_prep(const void* __restrict__ x,
    const void* __restrict__ Wqkv, const void* __restrict__ Wout,
    const void* __restrict__ bqkv, const void* __restrict__ bout,
    short* __restrict__ xb, short* __restrict__ WqT, short* __restrict__ WoT,
    float* __restrict__ bqf, float* __restrict__ bof, const int* __restrict__ flag)
{
    const int isf = *flag;
    const int t = threadIdx.x;
    const int b = blockIdx.x;
    if (b < 768) {
        size_t i = ((size_t)b*256 + t)*8;
        if (isf) {
            const float* xf = (const float*)x + i;
            short o[8];
            #pragma unroll
            for (int e = 0; e < 8; ++e) o[e] = f2b(xf[e]);
            *(int4*)(xb + i) = *(const int4*)o;
        } else {
            *(int4*)(xb + i) = *(const int4*)((const short*)x + i);
        }
    } else if (b < 1344) {
        // transpose W[KW][NW] -> WT[NW][KW] in 32x32 tiles
        int bb, NW; const void* W; short* WT;
        if (b < 1200) { bb = b - 768;  NW = QKVN; W = Wqkv; WT = WqT; }
        else          { bb = b - 1200; NW = DM;   W = Wout; WT = WoT; }
        int ntiles = NW >> 5;
        int kt = bb / ntiles, nt = bb % ntiles;
        int k0 = kt*32, n0 = nt*32;
        __shared__ float Ls[32][33];
        for (int idx = t; idx < 1024; idx += 256) {
            int r = idx >> 5, c = idx & 31;
            Ls[r][c] = ldin(W, (size_t)(k0+r)*NW + n0 + c, isf);
        }
        __syncthreads();
        for (int idx = t; idx < 1024; idx += 256) {
            int r2 = idx >> 5, c2 = idx & 31;
            WT[(size_t)(n0+r2)*DM + k0 + c2] = f2b(Ls[c2][r2]);
        }
    } else {
        int idx = (b - 1344)*256 + t;
        if (idx < QKVN) bqf[idx] = ldin(bqkv, idx, isf);
        else if (idx < QKVN + DM) bof[idx - QKVN] = ldin(bout, idx - QKVN, isf);
    }
}

// ---------------- K1: MFMA GEMM qkv = xb @ Wqkv + b; scatter q/k padded, v transposed
// 64x128 tile, BK=64, 4 waves each 32x64
__global__ __launch_bounds__(256) void k_qkv(const short* __restrict__ xb,
    const short* __restrict__ WT, const float* __restrict__ bias,
    short* __restrict__ q, short* __restrict__ k, short* __restrict__ vT)
{
    __shared__ __align__(16) short As[64*72];
    __shared__ __align__(16) short Bs[128*72];
    const int t = threadIdx.x;
    const int w = t >> 6, lane = t & 63, L = lane & 15, quad = lane >> 4;
    const int mt = blockIdx.x / 9, nt = blockIdx.x % 9;
    const int row0 = mt*64, col0 = nt*128;
    const int wm = w & 1, wn = w >> 1;
    float4v acc[2][4] = {};
    for (int k0 = 0; k0 < DM; k0 += 64) {
        __syncthreads();
        for (int c = t; c < 512; c += 256) {
            int row = c >> 3, k8 = c & 7;
            *(int4*)(&As[row*72 + k8*8]) = *(const int4*)(xb + (size_t)(row0+row)*DM + k0 + k8*8);
        }
        for (int c = t; c < 1024; c += 256) {
            int row = c >> 3, k8 = c & 7;
            *(int4*)(&Bs[row*72 + k8*8]) = *(const int4*)(WT + (size_t)(col0+row)*DM + k0 + k8*8);
        }
        __syncthreads();
        #pragma unroll
        for (int kc = 0; kc < 2; ++kc) {
            short8 a0 = *(const short8*)(&As[(32*wm + L)*72 + kc*32 + quad*8]);
            short8 a1 = *(const short8*)(&As[(32*wm + 16 + L)*72 + kc*32 + quad*8]);
            #pragma unroll
            for (int ni = 0; ni < 4; ++ni) {
                short8 bf = *(const short8*)(&Bs[(64*wn + 16*ni + L)*72 + kc*32 + quad*8]);
                acc[0][ni] = __builtin_amdgcn_mfma_f32_16x16x32_bf16(a0, bf, acc[0][ni], 0, 0, 0);
                acc[1][ni] = __builtin_amdgcn_mfma_f32_16x16x32_bf16(a1, bf, acc[1][ni], 0, 0, 0);
            }
        }
    }
    #pragma unroll
    for (int mi = 0; mi < 2; ++mi) {
        #pragma unroll
        for (int ni = 0; ni < 4; ++ni) {
            int col_g = col0 + 64*wn + 16*ni + L;
            int which = col_g / DM, c2 = col_g % DM;
            int hh = c2 / HD, dd = c2 % HD;
            float bv = bias[col_g];
            #pragma unroll
            for (int r = 0; r < 4; ++r) {
                int row_g = row0 + 32*wm + 16*mi + quad*4 + r;
                int bi = row_g >> 11, nn = row_g & (SEQ-1);
                short sv = f2b(acc[mi][ni][r] + bv);
                if (which == 0)      q[((size_t)(bi*NH+hh)*SEQ + nn)*HDP + dd] = sv;
                else if (which == 1) k[((size_t)(bi*NH+hh)*SEQ + nn)*HDP + dd] = sv;
                else                 vT[((size_t)(bi*NH+hh)*HD + dd)*SEQ + nn] = sv;
            }
        }
    }
}

// ---------------- K2: MFMA flash attention with distance bias.
__global__ __launch_bounds__(256) void k_attn(
    const short* __restrict__ qg, const short* __restrict__ kg, const short* __restrict__ vTg,
    const void* __restrict__ coords, const void* __restrict__ Wdist,
    const void* __restrict__ bdist, short* __restrict__ aob, const int* __restrict__ flag)
{
    __shared__ __align__(16) short Ks[64*72];
    __shared__ __align__(16) short Vs[48*72];
    __shared__ __align__(16) short Ps[4][16*72];
    __shared__ float cix[64], ciy[64], ciz[64];
    __shared__ float cjx[64], cjy[64], cjz[64];

    const int isf = *flag;
    const int t = threadIdx.x;
    const int w = t >> 6, lane = t & 63, L = lane & 15, quad = lane >> 4;
    const int bh = blockIdx.x >> 5, it = blockIdx.x & 31;
    const int bi = bh >> 3, hh = bh & 7;
    const int i0 = it * 64;
    const float scale = 0.14433756729740643f; // 1/sqrt(48)
    const float wd = ldin(Wdist, hh, isf), bd = ldin(bdist, hh, isf);

    // Q A-frags straight from global
    const short* qrow = qg + ((size_t)bh*SEQ + i0 + 16*w + L)*HDP;
    const short8 qa0 = *(const short8*)(qrow + quad*8);
    const short8 qa1 = *(const short8*)(qrow + 32 + quad*8);

    if (t < 64) {
        int gi = (bi*SEQ + i0 + t)*3;
        cix[t] = ldin(coords, gi, isf);
        ciy[t] = ldin(coords, gi+1, isf);
        ciz[t] = ldin(coords, gi+2, isf);
    }
    __syncthreads();
    float cxr[4], cyr[4], czr[4];
    #pragma unroll
    for (int r = 0; r < 4; ++r) {
        int ir = 16*w + quad*4 + r;
        cxr[r] = cix[ir]; cyr[r] = ciy[ir]; czr[r] = ciz[ir];
    }

    float mrow[4], lrow[4];
    #pragma unroll
    for (int r = 0; r < 4; ++r) { mrow[r] = -1e30f; lrow[r] = 0.f; }
    float4v accO[3] = {};

    for (int j0 = 0; j0 < SEQ; j0 += 64) {
        __syncthreads();
        for (int c = t; c < 512; c += 256) {
            int row = c >> 3, col8 = c & 7;
            *(int4*)(&Ks[row*72 + col8*8]) =
                *(const int4*)(kg + ((size_t)bh*SEQ + j0 + row)*HDP + col8*8);
        }
        for (int c = t; c < 384; c += 256) {
            int row = c >> 3, col8 = c & 7;
            *(int4*)(&Vs[row*72 + col8*8]) =
                *(const int4*)(vTg + ((size_t)bh*HD + row)*SEQ + j0 + col8*8);
        }
        if (t < 64) {
            int gj = (bi*SEQ + j0 + t)*3;
            cjx[t] = ldin(coords, gj, isf);
            cjy[t] = ldin(coords, gj+1, isf);
            cjz[t] = ldin(coords, gj+2, isf);
        }
        __syncthreads();

        // S = Q K^T
        float4v sacc[4] = {};
        #pragma unroll
        for (int nt = 0; nt < 4; ++nt) {
            short8 b0 = *(const short8*)(&Ks[(16*nt + L)*72 + quad*8]);
            sacc[nt] = __builtin_amdgcn_mfma_f32_16x16x32_bf16(qa0, b0, sacc[nt], 0, 0, 0);
            short8 b1 = *(const short8*)(&Ks[(16*nt + L)*72 + 32 + quad*8]);
            sacc[nt] = __builtin_amdgcn_mfma_f32_16x16x32_bf16(qa1, b1, sacc[nt], 0, 0, 0);
        }

        // logits + row max
        float lg[4][4];
        float tmax[4] = {-1e30f, -1e30f, -1e30f, -1e30f};
        #pragma unroll
        for (int nt = 0; nt < 4; ++nt) {
            float jx = cjx[16*nt + L], jy = cjy[16*nt + L], jz = cjz[16*nt + L];
            #pragma unroll
            for (int r = 0; r < 4; ++r) {
                float dx = cxr[r] - jx, dy = cyr[r] - jy, dz = czr[r] - jz;
                float dist = sqrtf(dx*dx + dy*dy + dz*dz);
                float v = sacc[nt][r]*scale + dist*wd + bd;
                lg[nt][r] = v;
                tmax[r] = fmaxf(tmax[r], v);
            }
        }
        #pragma unroll
        for (int r = 0; r < 4; ++r) {
            #pragma unroll
            for (int m = 1; m < 16; m <<= 1)
                tmax[r] = fmaxf(tmax[r], __shfl_xor(tmax[r], m, 16));
        }

        // online softmax
        float alpha[4], rsum[4];
        #pragma unroll
        for (int r = 0; r < 4; ++r) {
            float mn = fmaxf(mrow[r], tmax[r]);
            alpha[r] = __expf(mrow[r] - mn);
            mrow[r] = mn;
            rsum[r] = 0.f;
        }
        #pragma unroll
        for (int nt = 0; nt < 4; ++nt) {
            #pragma unroll
            for (int r = 0; r < 4; ++r) {
                float p = __expf(lg[nt][r] - mrow[r]);
                rsum[r] += p;
                Ps[w][(quad*4 + r)*72 + nt*16 + L] = f2b(p);
            }
        }
        #pragma unroll
        for (int r = 0; r < 4; ++r) {
            #pragma unroll
            for (int m = 1; m < 16; m <<= 1)
                rsum[r] += __shfl_xor(rsum[r], m, 16);
            lrow[r] = lrow[r]*alpha[r] + rsum[r];
        }
        #pragma unroll
        for (int dt = 0; dt < 3; ++dt)
            #pragma unroll
            for (int r = 0; r < 4; ++r)
                accO[dt][r] *= alpha[r];

        // O += P V   (B-frag: lane holds V^T[d=16dt+L][j=kchunk+quad*8..+7])
        short8 pa0 = *(const short8*)(&Ps[w][L*72 + quad*8]);
        short8 pa1 = *(const short8*)(&Ps[w][L*72 + 32 + quad*8]);
        #pragma unroll
        for (int dt = 0; dt < 3; ++dt) {
            short8 b0 = *(const short8*)(&Vs[(16*dt + L)*72 + quad*8]);
            accO[dt] = __builtin_amdgcn_mfma_f32_16x16x32_bf16(pa0, b0, accO[dt], 0, 0, 0);
            short8 b1 = *(const short8*)(&Vs[(16*dt + L)*72 + 32 + quad*8]);
            accO[dt] = __builtin_amdgcn_mfma_f32_16x16x32_bf16(pa1, b1, accO[dt], 0, 0, 0);
        }
    }

    float inv[4];
    #pragma unroll
    for (int r = 0; r < 4; ++r) inv[r] = 1.0f / lrow[r];
    #pragma unroll
    for (int r = 0; r < 4; ++r) {
        size_t row = (size_t)(bi*SEQ) + i0 + 16*w + quad*4 + r;
        #pragma unroll
        for (int dt = 0; dt < 3; ++dt)
            aob[row*DM + hh*HD + 16*dt + L] = f2b(accO[dt][r]*inv[r]);
    }
}

// ---------------- K3: MFMA GEMM out = aob @ Wout + b_out
__global__ __launch_bounds__(256) void k_out(const short* __restrict__ aob,
    const short* __restrict__ WT, const float* __restrict__ bias,
    void* __restrict__ out, const int* __restrict__ flag)
{
    __shared__ __align__(16) short As[64*72];
    __shared__ __align__(16) short Bs[128*72];
    const int isf = *flag;
    const int t = threadIdx.x;
    const int w = t >> 6, lane = t & 63, L = lane & 15, quad = lane >> 4;
    const int mt = blockIdx.x / 3, nt = blockIdx.x % 3;
    const int row0 = mt*64, col0 = nt*128;
    const int wm = w & 1, wn = w >> 1;
    float4v acc[2][4] = {};
    for (int k0 = 0; k0 < DM; k0 += 64) {
        __syncthreads();
        for (int c = t; c < 512; c += 256) {
            int row = c >> 3, k8 = c & 7;
            *(int4*)(&As[row*72 + k8*8]) = *(const int4*)(aob + (size_t)(row0+row)*DM + k0 + k8*8);
        }
        for (int c = t; c < 1024; c += 256) {
            int row = c >> 3, k8 = c & 7;
            *(int4*)(&Bs[row*72 + k8*8]) = *(const int4*)(WT + (size_t)(col0+row)*DM + k0 + k8*8);
        }
        __syncthreads();
        #pragma unroll
        for (int kc = 0; kc < 2; ++kc) {
            short8 a0 = *(const short8*)(&As[(32*wm + L)*72 + kc*32 + quad*8]);
            short8 a1 = *(const short8*)(&As[(32*wm + 16 + L)*72 + kc*32 + quad*8]);
            #pragma unroll
            for (int ni = 0; ni < 4; ++ni) {
                short8 bf = *(const short8*)(&Bs[(64*wn + 16*ni + L)*72 + kc*32 + quad*8]);
                acc[0][ni] = __builtin_amdgcn_mfma_f32_16x16x32_bf16(a0, bf, acc[0][ni], 0, 0, 0);
                acc[1][ni] = __builtin_amdgcn_mfma_f32_16x16x32_bf16(a1, bf, acc[1][ni], 0, 0, 0);
            }
        }
    }
    #pragma unroll
    for (int mi = 0; mi < 2; ++mi) {
        #pragma unroll
        for (int ni = 0; ni < 4; ++ni) {
            int col_g = col0 + 64*wn + 16*ni + L;
            float bv = bias[col_g];
            #pragma unroll
            for (int r = 0; r < 4; ++r) {
                int row_g = row0 + 32*wm + 16*mi + quad*4 + r;
                size_t oi = (size_t)row_g*DM + col_g;
                float val = acc[mi][ni][r] + bv;
                if (isf) ((float*)out)[oi] = val;
                else     ((bf16*)out)[oi]  = __float2bfloat16(val);
            }
        }
    }
}

extern "C" void kernel_launch(void* const* d_in, const int* in_sizes, int n_in,
                              void* d_out, int out_size, void* d_ws, size_t ws_size,
                              hipStream_t stream) {
    const void* x      = d_in[0];
    const void* coords = d_in[1];
    const void* Wqkv   = d_in[2];
    const void* bqkv   = d_in[3];
    const void* Wdist  = d_in[4];
    const void* bdist  = d_in[5];
    const void* Wout   = d_in[6];
    const void* bout   = d_in[7];

    short* qb  = (short*)d_ws;                 // [16][2048][64]
    short* kb  = qb  + (size_t)BH*SEQ*HDP;     // [16][2048][64]
    short* vT  = kb  + (size_t)BH*SEQ*HDP;     // [16][48][2048]
    short* aob = vT  + (size_t)BH*HD*SEQ;      // [4096][384]
    short* xb  = aob + (size_t)NB*SEQ*DM;      // [4096][384]
    short* WqT = xb  + (size_t)NB*SEQ*DM;      // [1152][384]
    short* WoT = WqT + (size_t)QKVN*DM;        // [384][384]
    float* bqf = (float*)(WoT + (size_t)DM*DM);
    float* bof = bqf + QKVN;
    int* flag  = (int*)(bof + DM);

    // zero q/k pads (d 48..63 must be 0); qb,kb contiguous
    hipMemsetAsync(qb, 0, (size_t)2*BH*SEQ*HDP*sizeof(short), stream);

    k_detect<<<dim3(1), dim3(64), 0, stream>>>(x, flag);
    k_prep<<<dim3(1350), dim3(256), 0, stream>>>(x, Wqkv, Wout, bqkv, bout,
                                                 xb, WqT, WoT, bqf, bof, flag);
    k_qkv<<<dim3(64*9), dim3(256), 0, stream>>>(xb, WqT, bqf, qb, kb, vT);
    k_attn<<<dim3(BH*32), dim3(256), 0, stream>>>(qb, kb, vT, coords, Wdist, bdist, aob, flag);
    k_out<<<dim3(64*3), dim3(256), 0, stream>>>(aob, WoT, bof, d_out, flag);
}

// Round 5
// 173.310 us; speedup vs baseline: 5.1588x; 1.4104x over previous
//
#include <hip/hip_runtime.h>
#include <hip/hip_bf16.h>

#define NB 2
#define SEQ 2048
#define DM 384
#define NH 8
#define HD 48
#define QKVN 1152
#define BH (NB*NH)

typedef __hip_bfloat16 bf16;
typedef __attribute__((ext_vector_type(8))) short short8;
typedef __attribute__((ext_vector_type(4))) float float4v;

static __device__ __forceinline__ float bf2f(bf16 v){ return __bfloat162float(v); }
static __device__ __forceinline__ float ldin(const void* p, size_t i, int isf){
    return isf ? ((const float*)p)[i] : bf2f(((const bf16*)p)[i]);
}
// fp32 -> bf16 bits, RNE
static __device__ __forceinline__ short f2b(float f){
    union { float f; unsigned u; } a; a.f = f;
    unsigned r = a.u + 0x7FFFu + ((a.u >> 16) & 1u);
    return (short)(r >> 16);
}
// pack two fp32 -> bf16x2 (round-half-up, cheap)
static __device__ __forceinline__ unsigned pk2(float a, float b){
    union { float f; unsigned u; } ua, ub; ua.f = a; ub.f = b;
    return ((ua.u + 0x8000u) >> 16) | ((ub.u + 0x8000u) & 0xFFFF0000u);
}
static __device__ __forceinline__ float bflo(unsigned u){
    union { unsigned u; float f; } a; a.u = u << 16; return a.f;
}
static __device__ __forceinline__ float bfhi(unsigned u){
    union { unsigned u; float f; } a; a.u = u & 0xFFFF0000u; return a.f;
}

// ---------------- K0: detect input dtype (0 = bf16, 1 = fp32)
__global__ void k_detect(const void* __restrict__ x, int* __restrict__ flag)
{
    int t = threadIdx.x;
    const bf16* xb = (const bf16*)x;
    float v = bf2f(xb[2*t]);
    float a = fabsf(v);
    int good = (v == 0.0f) || (a > 9.765625e-4f && a < 1024.0f);
    unsigned long long m = __ballot(good);
    if (t == 0) *flag = (__popcll(m) >= 32) ? 0 : 1;
}

// ---------------- K_prep: xb = bf16(x); WqkvT/WoutT transposed bf16; biases fp32
__global__ __launch_bounds__(256) void k_prep(const void* __restrict__ x,
    const void* __restrict__ Wqkv, const void* __restrict__ Wout,
    const void* __restrict__ bqkv, const void* __restrict__ bout,
    short* __restrict__ xb, short* __restrict__ WqT, short* __restrict__ WoT,
    float* __restrict__ bqf, float* __restrict__ bof, const int* __restrict__ flag)
{
    const int isf = *flag;
    const int t = threadIdx.x;
    const int b = blockIdx.x;
    if (b < 768) {
        size_t i = ((size_t)b*256 + t)*8;
        if (isf) {
            const float* xf = (const float*)x + i;
            short o[8];
            #pragma unroll
            for (int e = 0; e < 8; ++e) o[e] = f2b(xf[e]);
            *(int4*)(xb + i) = *(const int4*)o;
        } else {
            *(int4*)(xb + i) = *(const int4*)((const short*)x + i);
        }
    } else if (b < 1344) {
        int bb, NW; const void* W; short* WT;
        if (b < 1200) { bb = b - 768;  NW = QKVN; W = Wqkv; WT = WqT; }
        else          { bb = b - 1200; NW = DM;   W = Wout; WT = WoT; }
        int ntiles = NW >> 5;
        int kt = bb / ntiles, nt = bb % ntiles;
        int k0 = kt*32, n0 = nt*32;
        __shared__ float Ls[32][33];
        for (int idx = t; idx < 1024; idx += 256) {
            int r = idx >> 5, c = idx & 31;
            Ls[r][c] = ldin(W, (size_t)(k0+r)*NW + n0 + c, isf);
        }
        __syncthreads();
        for (int idx = t; idx < 1024; idx += 256) {
            int r2 = idx >> 5, c2 = idx & 31;
            WT[(size_t)(n0+r2)*DM + k0 + c2] = f2b(Ls[c2][r2]);
        }
    } else {
        int idx = (b - 1344)*256 + t;
        if (idx < QKVN) bqf[idx] = ldin(bqkv, idx, isf);
        else if (idx < QKVN + DM) bof[idx - QKVN] = ldin(bout, idx - QKVN, isf);
    }
}

// ---------------- K_dist: dist8[b][jt(32)][jg(8)][i(2048)][8 j] bf16
__global__ __launch_bounds__(256) void k_dist(const void* __restrict__ coords,
    short* __restrict__ dist8, const int* __restrict__ flag)
{
    const int isf = *flag;
    const int t = threadIdx.x;
    const int bid = blockIdx.x;          // b*256 + jt*8 + jg
    const int b = bid >> 8;
    const int j0 = (bid & 255) * 8;
    __shared__ float cjx[8], cjy[8], cjz[8];
    if (t < 8) {
        int gj = (b*SEQ + j0 + t)*3;
        cjx[t] = ldin(coords, gj, isf);
        cjy[t] = ldin(coords, gj+1, isf);
        cjz[t] = ldin(coords, gj+2, isf);
    }
    __syncthreads();
    #pragma unroll
    for (int ii = 0; ii < 8; ++ii) {
        int i = ii*256 + t;
        int gi = (b*SEQ + i)*3;
        float x = ldin(coords, gi, isf), y = ldin(coords, gi+1, isf), z = ldin(coords, gi+2, isf);
        short o[8];
        #pragma unroll
        for (int e = 0; e < 8; ++e) {
            float dx = x - cjx[e], dy = y - cjy[e], dz = z - cjz[e];
            o[e] = f2b(sqrtf(dx*dx + dy*dy + dz*dz));
        }
        *(int4*)(dist8 + ((size_t)bid*SEQ + i)*8) = *(const int4*)o;
    }
}

// ---------------- K1: MFMA GEMM qkv = xb @ Wqkv + b; scatter to fragment-linear q/k/v
__global__ __launch_bounds__(256) void k_qkv(const short* __restrict__ xb,
    const short* __restrict__ WT, const float* __restrict__ bias,
    short* __restrict__ qg2, short* __restrict__ kg2, short* __restrict__ vg2)
{
    __shared__ __align__(16) short As[64*72];
    __shared__ __align__(16) short Bs[128*72];
    const int t = threadIdx.x;
    const int w = t >> 6, lane = t & 63, L = lane & 15, quad = lane >> 4;
    const int mt = blockIdx.x / 9, nt = blockIdx.x % 9;
    const int row0 = mt*64, col0 = nt*128;
    const int wm = w & 1, wn = w >> 1;
    float4v acc[2][4] = {};
    for (int k0 = 0; k0 < DM; k0 += 64) {
        __syncthreads();
        for (int c = t; c < 512; c += 256) {
            int row = c >> 3, k8 = c & 7;
            *(int4*)(&As[row*72 + k8*8]) = *(const int4*)(xb + (size_t)(row0+row)*DM + k0 + k8*8);
        }
        for (int c = t; c < 1024; c += 256) {
            int row = c >> 3, k8 = c & 7;
            *(int4*)(&Bs[row*72 + k8*8]) = *(const int4*)(WT + (size_t)(col0+row)*DM + k0 + k8*8);
        }
        __syncthreads();
        #pragma unroll
        for (int kc = 0; kc < 2; ++kc) {
            short8 a0 = *(const short8*)(&As[(32*wm + L)*72 + kc*32 + quad*8]);
            short8 a1 = *(const short8*)(&As[(32*wm + 16 + L)*72 + kc*32 + quad*8]);
            #pragma unroll
            for (int ni = 0; ni < 4; ++ni) {
                short8 bf = *(const short8*)(&Bs[(64*wn + 16*ni + L)*72 + kc*32 + quad*8]);
                acc[0][ni] = __builtin_amdgcn_mfma_f32_16x16x32_bf16(a0, bf, acc[0][ni], 0, 0, 0);
                acc[1][ni] = __builtin_amdgcn_mfma_f32_16x16x32_bf16(a1, bf, acc[1][ni], 0, 0, 0);
            }
        }
    }
    #pragma unroll
    for (int mi = 0; mi < 2; ++mi) {
        #pragma unroll
        for (int ni = 0; ni < 4; ++ni) {
            int col_g = col0 + 64*wn + 16*ni + L;
            int which = col_g / DM, c2 = col_g % DM;
            int hh = c2 / HD, dd = c2 % HD;
            float bv = bias[col_g];
            #pragma unroll
            for (int r = 0; r < 4; ++r) {
                int row_g = row0 + 32*wm + 16*mi + quad*4 + r;
                int bi = row_g >> 11, nn = row_g & (SEQ-1);
                int bh = bi*NH + hh;
                short sv = f2b(acc[mi][ni][r] + bv);
                if (which == 2) {
                    // vg2[bh][nn>>6][dd>>4][ (nn>>5)&1 ][ (nn>>3)&3 ][ dd&15 ][ nn&7 ]
                    size_t idx = (((((size_t)bh*32 + (nn>>6))*3 + (dd>>4))*2 + ((nn>>5)&1))*4 + ((nn>>3)&3))*128
                                 + (size_t)(dd & 15)*8 + (nn & 7);
                    vg2[idx] = sv;
                } else {
                    // qg2/kg2[bh][nn>>4][dd>>5][ (dd>>3)&3 ][ nn&15 ][ dd&7 ]
                    size_t idx = ((((size_t)bh*128 + (nn>>4))*2 + (dd>>5))*4 + ((dd>>3)&3))*128
                                 + (size_t)(nn & 15)*8 + (dd & 7);
                    if (which) kg2[idx] = sv; else qg2[idx] = sv;
                }
            }
        }
    }
}

// ---------------- K2: MFMA flash attention, S^T form, no-max softmax, j-split x2
__global__ __launch_bounds__(256, 4) void k_attn(
    const short* __restrict__ qg2, const short* __restrict__ kg2, const short* __restrict__ vg2,
    const short* __restrict__ dist8, const void* __restrict__ Wdist,
    const void* __restrict__ bdist, float* __restrict__ partO, float* __restrict__ partL,
    const int* __restrict__ flag)
{
    __shared__ __align__(16) short PsT[4][16*72];
    const int isf = *flag;
    const int t = threadIdx.x;
    const int w = t >> 6, lane = t & 63, L = lane & 15, q = lane >> 4;
    const int bid = blockIdx.x;
    const int jsb = bid & 1, it = (bid >> 1) & 31, bh = bid >> 6;
    const int bi = bh >> 3, hh = bh & 7;
    const int i0 = it*64;
    const float scale = 0.14433756729740643f;   // 1/sqrt(48)
    const float wd = ldin(Wdist, hh, isf), bd = ldin(bdist, hh, isf);

    // Q A-frags: qg2[bh][it*4+w][kc][q][L][8]
    const short* qbase = qg2 + (((size_t)bh*128 + it*4 + w)*2)*512;
    const short8 qa0 = *(const short8*)(qbase + (size_t)(q*16 + L)*8);
    const short8 qa1 = *(const short8*)(qbase + 512 + (size_t)(q*16 + L)*8);

    const int iL = i0 + 16*w + L;               // this lane's softmax column (i)
    float rsum = 0.f;
    float4v accO[3] = {};

    const size_t kBH = (size_t)bh*131072;       // 128*2*512
    const size_t vBH = (size_t)bh*98304;        // 32*3*2*512
    const size_t dB  = (size_t)bi*256*SEQ*8;

    const int jlo = jsb*(SEQ/2), jhi = jlo + SEQ/2;
    for (int j0 = jlo; j0 < jhi; j0 += 64) {
        float4v sacc[4] = {};
        #pragma unroll
        for (int nt = 0; nt < 4; ++nt) {
            const short* kb = kg2 + kBH + ((size_t)((j0>>4) + nt))*1024;
            short8 kf0 = *(const short8*)(kb + (size_t)(q*16 + L)*8);
            sacc[nt] = __builtin_amdgcn_mfma_f32_16x16x32_bf16(kf0, qa0, sacc[nt], 0, 0, 0);
            short8 kf1 = *(const short8*)(kb + 512 + (size_t)(q*16 + L)*8);
            sacc[nt] = __builtin_amdgcn_mfma_f32_16x16x32_bf16(kf1, qa1, sacc[nt], 0, 0, 0);
        }
        // logits -> p -> PsT (S^T: lane holds rows j=16nt+4q+r, col i=L)
        #pragma unroll
        for (int nt = 0; nt < 4; ++nt) {
            const short* dp = dist8 + dB + (((size_t)(j0>>6)*8 + 2*nt + (q>>1))*SEQ + iL)*8 + 4*(q&1);
            uint2 du = *(const uint2*)dp;
            float d0 = bflo(du.x), d1 = bfhi(du.x), d2 = bflo(du.y), d3 = bfhi(du.y);
            float p0 = __expf(fmaf(sacc[nt][0], scale, fmaf(d0, wd, bd)));
            float p1 = __expf(fmaf(sacc[nt][1], scale, fmaf(d1, wd, bd)));
            float p2 = __expf(fmaf(sacc[nt][2], scale, fmaf(d2, wd, bd)));
            float p3 = __expf(fmaf(sacc[nt][3], scale, fmaf(d3, wd, bd)));
            rsum += (p0 + p1) + (p2 + p3);
            uint2 pw; pw.x = pk2(p0, p1); pw.y = pk2(p2, p3);
            *(uint2*)(&PsT[w][L*72 + 16*nt + 4*q]) = pw;
        }
        // P A-frags (A[m=i=L][k=j=q*8..]); same-wave RAW, no barrier needed
        short8 pa0 = *(const short8*)(&PsT[w][L*72 + q*8]);
        short8 pa1 = *(const short8*)(&PsT[w][L*72 + 32 + q*8]);
        #pragma unroll
        for (int dt = 0; dt < 3; ++dt) {
            const short* vb = vg2 + vBH + ((size_t)(j0>>6)*3 + dt)*1024;
            short8 vf0 = *(const short8*)(vb + (size_t)(q*16 + L)*8);
            accO[dt] = __builtin_amdgcn_mfma_f32_16x16x32_bf16(pa0, vf0, accO[dt], 0, 0, 0);
            short8 vf1 = *(const short8*)(vb + 512 + (size_t)(q*16 + L)*8);
            accO[dt] = __builtin_amdgcn_mfma_f32_16x16x32_bf16(pa1, vf1, accO[dt], 0, 0, 0);
        }
    }
    // l partial: sum over quads for column i=L
    rsum += __shfl_xor(rsum, 16);
    rsum += __shfl_xor(rsum, 32);
    const size_t pbase = ((size_t)(jsb*BH + bh))*SEQ;
    if (q == 0) partL[pbase + iL] = rsum;
    #pragma unroll
    for (int dt = 0; dt < 3; ++dt)
        #pragma unroll
        for (int r = 0; r < 4; ++r)
            partO[(pbase + i0 + 16*w + 4*q + r)*48 + 16*dt + L] = accO[dt][r];
}

// ---------------- K_red: aob[row][col] = (sum_js partO) / (sum_js partL), bf16
__global__ __launch_bounds__(256) void k_red(const float* __restrict__ partO,
    const float* __restrict__ partL, short* __restrict__ aob)
{
    int g = blockIdx.x*256 + threadIdx.x;       // 4096*48 groups of 8
    int row = g / 48, cg = g % 48;
    int bi = row >> 11, i = row & (SEQ-1);
    int hh = cg / 6, d8 = (cg % 6)*8;
    int bh = bi*NH + hh;
    size_t o0 = ((size_t)bh*SEQ + i)*48 + d8;
    size_t o1 = ((size_t)(BH + bh)*SEQ + i)*48 + d8;
    float4 a0 = *(const float4*)(partO + o0);
    float4 a1 = *(const float4*)(partO + o0 + 4);
    float4 b0 = *(const float4*)(partO + o1);
    float4 b1 = *(const float4*)(partO + o1 + 4);
    float l = partL[(size_t)bh*SEQ + i] + partL[(size_t)(BH + bh)*SEQ + i];
    float inv = 1.0f / l;
    short o[8];
    o[0] = f2b((a0.x + b0.x)*inv); o[1] = f2b((a0.y + b0.y)*inv);
    o[2] = f2b((a0.z + b0.z)*inv); o[3] = f2b((a0.w + b0.w)*inv);
    o[4] = f2b((a1.x + b1.x)*inv); o[5] = f2b((a1.y + b1.y)*inv);
    o[6] = f2b((a1.z + b1.z)*inv); o[7] = f2b((a1.w + b1.w)*inv);
    *(int4*)(aob + (size_t)row*DM + hh*HD + d8) = *(const int4*)o;
}

// ---------------- K3: MFMA GEMM out = aob @ Wout + b_out
__global__ __launch_bounds__(256) void k_out(const short* __restrict__ aob,
    const short* __restrict__ WT, const float* __restrict__ bias,
    void* __restrict__ out, const int* __restrict__ flag)
{
    __shared__ __align__(16) short As[64*72];
    __shared__ __align__(16) short Bs[128*72];
    const int isf = *flag;
    const int t = threadIdx.x;
    const int w = t >> 6, lane = t & 63, L = lane & 15, quad = lane >> 4;
    const int mt = blockIdx.x / 3, nt = blockIdx.x % 3;
    const int row0 = mt*64, col0 = nt*128;
    const int wm = w & 1, wn = w >> 1;
    float4v acc[2][4] = {};
    for (int k0 = 0; k0 < DM; k0 += 64) {
        __syncthreads();
        for (int c = t; c < 512; c += 256) {
            int row = c >> 3, k8 = c & 7;
            *(int4*)(&As[row*72 + k8*8]) = *(const int4*)(aob + (size_t)(row0+row)*DM + k0 + k8*8);
        }
        for (int c = t; c < 1024; c += 256) {
            int row = c >> 3, k8 = c & 7;
            *(int4*)(&Bs[row*72 + k8*8]) = *(const int4*)(WT + (size_t)(col0+row)*DM + k0 + k8*8);
        }
        __syncthreads();
        #pragma unroll
        for (int kc = 0; kc < 2; ++kc) {
            short8 a0 = *(const short8*)(&As[(32*wm + L)*72 + kc*32 + quad*8]);
            short8 a1 = *(const short8*)(&As[(32*wm + 16 + L)*72 + kc*32 + quad*8]);
            #pragma unroll
            for (int ni = 0; ni < 4; ++ni) {
                short8 bf = *(const short8*)(&Bs[(64*wn + 16*ni + L)*72 + kc*32 + quad*8]);
                acc[0][ni] = __builtin_amdgcn_mfma_f32_16x16x32_bf16(a0, bf, acc[0][ni], 0, 0, 0);
                acc[1][ni] = __builtin_amdgcn_mfma_f32_16x16x32_bf16(a1, bf, acc[1][ni], 0, 0, 0);
            }
        }
    }
    #pragma unroll
    for (int mi = 0; mi < 2; ++mi) {
        #pragma unroll
        for (int ni = 0; ni < 4; ++ni) {
            int col_g = col0 + 64*wn + 16*ni + L;
            float bv = bias[col_g];
            #pragma unroll
            for (int r = 0; r < 4; ++r) {
                int row_g = row0 + 32*wm + 16*mi + quad*4 + r;
                size_t oi = (size_t)row_g*DM + col_g;
                float val = acc[mi][ni][r] + bv;
                if (isf) ((float*)out)[oi] = val;
                else     ((bf16*)out)[oi]  = __float2bfloat16(val);
            }
        }
    }
}

extern "C" void kernel_launch(void* const* d_in, const int* in_sizes, int n_in,
                              void* d_out, int out_size, void* d_ws, size_t ws_size,
                              hipStream_t stream) {
    const void* x      = d_in[0];
    const void* coords = d_in[1];
    const void* Wqkv   = d_in[2];
    const void* bqkv   = d_in[3];
    const void* Wdist  = d_in[4];
    const void* bdist  = d_in[5];
    const void* Wout   = d_in[6];
    const void* bout   = d_in[7];

    short* qg2   = (short*)d_ws;                       // 2,097,152 shorts (frag-linear)
    short* kg2   = qg2  + (size_t)2097152;             // 2,097,152
    short* vg2   = kg2  + (size_t)2097152;             // 1,572,864
    short* dist8 = vg2  + (size_t)1572864;             // 8,388,608 (16 MB)
    short* aob   = dist8 + (size_t)8388608;            // 1,572,864
    short* xb    = aob  + (size_t)1572864;             // 1,572,864
    short* WqT   = xb   + (size_t)1572864;             // 442,368
    short* WoT   = WqT  + (size_t)442368;              // 147,456
    float* partO = (float*)(WoT + (size_t)147456);     // 3,145,728 floats
    float* partL = partO + (size_t)3145728;            // 65,536
    float* bqf   = partL + (size_t)65536;
    float* bof   = bqf + QKVN;
    int*   flag  = (int*)(bof + DM);

    // zero q/k fragment buffers (d=48..63 pads must be 0)
    hipMemsetAsync(qg2, 0, (size_t)2*2097152*sizeof(short), stream);

    k_detect<<<dim3(1), dim3(64), 0, stream>>>(x, flag);
    k_prep<<<dim3(1350), dim3(256), 0, stream>>>(x, Wqkv, Wout, bqkv, bout,
                                                 xb, WqT, WoT, bqf, bof, flag);
    k_dist<<<dim3(512), dim3(256), 0, stream>>>(coords, dist8, flag);
    k_qkv<<<dim3(64*9), dim3(256), 0, stream>>>(xb, WqT, bqf, qg2, kg2, vg2);
    k_attn<<<dim3(1024), dim3(256), 0, stream>>>(qg2, kg2, vg2, dist8, Wdist, bdist,
                                                 partO, partL, flag);
    k_red<<<dim3(768), dim3(256), 0, stream>>>(partO, partL, aob);
    k_out<<<dim3(64*3), dim3(256), 0, stream>>>(aob, WoT, bof, d_out, flag);
}